// Round 1
// baseline (15512.813 us; speedup 1.0000x reference)
//
#include <hip/hip_runtime.h>
#include <math.h>

#define H 256
#define H4 1024
#define Bsz 1024
#define TIN 168
#define TOUT 24
#define Fh 8
#define XROW (TIN*Fh)

__device__ __forceinline__ float sigmf(float x) { return 1.0f / (1.0f + expf(-x)); }

// ---------------------------------------------------------------------------
// Fused LSTM step: gates GEMM (h @ Whh^T [+ second GEMM or small x-term]) with
// in-kernel 4-gate activation + c/h update.
// Tile: 64 rows x (16 cols x 4 gates). Threads 256, 4x4 micro-tile.
// MODE 0: encoder L0 (x-term K=8 gathered in epilogue)
// MODE 1: encoder L1 (second full K=256 GEMM: h0_new @ Wih1^T)
// MODE 2: decoder (blockIdx.z = f, rank-1 x-term xi[b]*Wih[col])
// ---------------------------------------------------------------------------
template<int MODE>
__global__ __launch_bounds__(256)
void lstm_step_kernel(const float* __restrict__ hA, const float* __restrict__ Whh,
                      const float* __restrict__ A2, const float* __restrict__ W2,
                      const float* __restrict__ xptr, const float* __restrict__ Wx,
                      const float* __restrict__ bih, const float* __restrict__ bhh,
                      float* __restrict__ cbuf, float* __restrict__ hout)
{
    __shared__ float As[16][68];
    __shared__ float Ws[16][68];
    const int tid = threadIdx.x;
    const int tx = tid & 15, ty = tid >> 4;
    const int r0 = blockIdx.x * 64;
    const int j0 = blockIdx.y * 16;
    int f = 0;
    if (MODE == 2) {
        f = blockIdx.z;
        size_t BH = (size_t)Bsz * H;
        hA   += (size_t)f * BH;
        Whh  += (size_t)f * H4 * H;
        Wx   += (size_t)f * H4;
        bih  += (size_t)f * H4;
        bhh  += (size_t)f * H4;
        cbuf += (size_t)f * BH;
        hout += (size_t)f * BH;
    }
    float acc[4][4] = {};  // [row_i][gate]
    const int npass = (MODE == 1) ? 2 : 1;
    for (int pass = 0; pass < npass; ++pass) {
        const float* Ap = (pass == 0) ? hA : A2;
        const float* Wp = (pass == 0) ? Whh : W2;
        for (int k0 = 0; k0 < H; k0 += 16) {
#pragma unroll
            for (int p = 0; p < 4; ++p) {
                int rr = ty + p * 16;
                As[tx][rr] = Ap[(size_t)(r0 + rr) * H + k0 + tx];
            }
#pragma unroll
            for (int p = 0; p < 4; ++p) {
                int c = ty + p * 16;          // c = jl*4 + g
                int jl = c >> 2, g = c & 3;
                Ws[tx][c] = Wp[(size_t)(g * H + j0 + jl) * H + k0 + tx];
            }
            __syncthreads();
#pragma unroll
            for (int k = 0; k < 16; ++k) {
                const float4 a4 = *(const float4*)&As[k][ty * 4];
                const float4 b4 = *(const float4*)&Ws[k][tx * 4];
                const float a_[4] = {a4.x, a4.y, a4.z, a4.w};
                const float b_[4] = {b4.x, b4.y, b4.z, b4.w};
#pragma unroll
                for (int i = 0; i < 4; ++i)
#pragma unroll
                    for (int g = 0; g < 4; ++g)
                        acc[i][g] = fmaf(a_[i], b_[g], acc[i][g]);
            }
            __syncthreads();
        }
    }
    const int jj = j0 + tx;
#pragma unroll
    for (int i = 0; i < 4; ++i) {
        const int r = r0 + ty * 4 + i;
        float pre[4];
#pragma unroll
        for (int g = 0; g < 4; ++g)
            pre[g] = acc[i][g] + bih[g * H + jj] + bhh[g * H + jj];
        if (MODE == 0) {
            const float* xr = xptr + (size_t)r * XROW;
#pragma unroll
            for (int g = 0; g < 4; ++g) {
                float s = 0.f;
#pragma unroll
                for (int ki = 0; ki < Fh; ++ki)
                    s = fmaf(xr[ki], Wx[(size_t)(g * H + jj) * Fh + ki], s);
                pre[g] += s;
            }
        }
        if (MODE == 2) {
            const float xi = xptr[r * Fh + f];
#pragma unroll
            for (int g = 0; g < 4; ++g)
                pre[g] = fmaf(xi, Wx[g * H + jj], pre[g]);
        }
        const float ig = sigmf(pre[0]);
        const float fg = sigmf(pre[1]);
        const float gg = tanhf(pre[2]);
        const float og = sigmf(pre[3]);
        const size_t off = (size_t)r * H + jj;
        const float cn = fg * cbuf[off] + ig * gg;
        cbuf[off] = cn;
        hout[off] = og * tanhf(cn);
    }
}

// ---------------------------------------------------------------------------
// Generic tiled f32 GEMM: C = act(A @ B' + bias), 64x64 tile, 4x4 micro-tile.
// BT=0: B row-major (N,K) i.e. C = A @ B^T.   BT=1: B is (K,N).
// ACT=0: +bias.  ACT=1: +bias, leaky_relu(0.01).  ACT=2: *alpha (no bias).
// blockIdx.z strides all pointers (per-f batching).
// ---------------------------------------------------------------------------
template<int BT, int ACT>
__global__ __launch_bounds__(256)
void gemm_kernel(const float* __restrict__ A, int lda, size_t sA,
                 const float* __restrict__ Bm, int ldb, size_t sB,
                 const float* __restrict__ bias, int sbias,
                 float* __restrict__ C, int ldc, size_t sC,
                 int K, float alpha)
{
    __shared__ float As[16][68];
    __shared__ float Bs[16][68];
    const int tid = threadIdx.x;
    const int tx = tid & 15, ty = tid >> 4;
    const int r0 = blockIdx.x * 64;
    const int n0 = blockIdx.y * 64;
    const int z = blockIdx.z;
    A  += (size_t)z * sA;
    Bm += (size_t)z * sB;
    C  += (size_t)z * sC;
    if (ACT != 2) bias += (size_t)z * sbias;
    float acc[4][4] = {};
    for (int k0 = 0; k0 < K; k0 += 16) {
#pragma unroll
        for (int p = 0; p < 4; ++p) {
            int rr = ty + p * 16;
            As[tx][rr] = A[(size_t)(r0 + rr) * lda + k0 + tx];
        }
#pragma unroll
        for (int p = 0; p < 4; ++p) {
            if (BT == 0) {
                int c = ty + p * 16;
                Bs[tx][c] = Bm[(size_t)(n0 + c) * ldb + k0 + tx];
            } else {
                int e = tid + p * 256;
                int kk = e >> 6, c = e & 63;
                Bs[kk][c] = Bm[(size_t)(k0 + kk) * ldb + n0 + c];
            }
        }
        __syncthreads();
#pragma unroll
        for (int k = 0; k < 16; ++k) {
            const float4 a4 = *(const float4*)&As[k][ty * 4];
            const float4 b4 = *(const float4*)&Bs[k][tx * 4];
            const float a_[4] = {a4.x, a4.y, a4.z, a4.w};
            const float b_[4] = {b4.x, b4.y, b4.z, b4.w};
#pragma unroll
            for (int i = 0; i < 4; ++i)
#pragma unroll
                for (int j = 0; j < 4; ++j)
                    acc[i][j] = fmaf(a_[i], b_[j], acc[i][j]);
        }
        __syncthreads();
    }
#pragma unroll
    for (int i = 0; i < 4; ++i) {
        const int r = r0 + ty * 4 + i;
        float4 o;
        float* op = &o.x;
#pragma unroll
        for (int j = 0; j < 4; ++j) {
            float v = acc[i][j];
            const int n = n0 + tx * 4 + j;
            if (ACT == 0) v += bias[n];
            if (ACT == 1) { v += bias[n]; v = (v > 0.f) ? v : 0.01f * v; }
            if (ACT == 2) v *= alpha;
            op[j] = v;
        }
        *(float4*)&C[(size_t)r * ldc + n0 + tx * 4] = o;
    }
}

// Row softmax over 1024-wide rows (grid = F*B rows).
__global__ __launch_bounds__(256)
void softmax_kernel(float* __restrict__ attn)
{
    const size_t row = blockIdx.x;
    float* p = attn + row * Bsz;
    const int tid = threadIdx.x;
    float4 v = ((float4*)p)[tid];
    float m = fmaxf(fmaxf(v.x, v.y), fmaxf(v.z, v.w));
#pragma unroll
    for (int s = 1; s < 64; s <<= 1) m = fmaxf(m, __shfl_xor(m, s));
    __shared__ float red[4];
    __shared__ float red2[4];
    if ((tid & 63) == 0) red[tid >> 6] = m;
    __syncthreads();
    m = fmaxf(fmaxf(red[0], red[1]), fmaxf(red[2], red[3]));
    v.x = expf(v.x - m); v.y = expf(v.y - m); v.z = expf(v.z - m); v.w = expf(v.w - m);
    float s4 = v.x + v.y + v.z + v.w;
#pragma unroll
    for (int s = 1; s < 64; s <<= 1) s4 += __shfl_xor(s4, s);
    if ((tid & 63) == 0) red2[tid >> 6] = s4;
    __syncthreads();
    const float inv = 1.0f / (red2[0] + red2[1] + red2[2] + red2[3]);
    v.x *= inv; v.y *= inv; v.z *= inv; v.w *= inv;
    ((float4*)p)[tid] = v;
}

// fc2 + leaky + write out[:, t, :] and feed back din. One wave per (f,b) row.
__global__ __launch_bounds__(256)
void fc2_out_kernel(const float* __restrict__ ao, const float* __restrict__ f2W,
                    const float* __restrict__ f2b, float* __restrict__ out,
                    float* __restrict__ din, int t)
{
    const int tid = threadIdx.x;
    const int lane = tid & 63, w = tid >> 6;
    const size_t idx = (size_t)blockIdx.x * 4 + w;  // 0..F*B-1
    const int f = (int)(idx >> 10), b = (int)(idx & 1023);
    const float* row = ao + ((size_t)f * Bsz + b) * H;
    const float4 v = ((const float4*)row)[lane];
    const float4 wv = ((const float4*)(f2W + f * H))[lane];
    float s = v.x * wv.x + v.y * wv.y + v.z * wv.z + v.w * wv.w;
#pragma unroll
    for (int d = 1; d < 64; d <<= 1) s += __shfl_xor(s, d);
    if (lane == 0) {
        s += f2b[f];
        s = (s > 0.f) ? s : 0.01f * s;
        out[(size_t)b * (TOUT * Fh) + (size_t)t * Fh + f] = s;
        din[b * Fh + f] = s;
    }
}

// (h0+h1)/2, (c0+c1)/2 broadcast to all F decoder states; din = x[:,-1,:].
__global__ __launch_bounds__(256)
void combine_init_kernel(const float* __restrict__ h0, const float* __restrict__ c0,
                         const float* __restrict__ h1, const float* __restrict__ c1,
                         const float* __restrict__ x,
                         float* __restrict__ dh, float* __restrict__ dc,
                         float* __restrict__ din)
{
    const size_t idx = (size_t)blockIdx.x * 256 + threadIdx.x;  // 0..B*H-1
    const float hm = 0.5f * (h0[idx] + h1[idx]);
    const float cm = 0.5f * (c0[idx] + c1[idx]);
    const size_t BH = (size_t)Bsz * H;
#pragma unroll
    for (int f = 0; f < Fh; ++f) { dh[f * BH + idx] = hm; dc[f * BH + idx] = cm; }
    if (idx < (size_t)Bsz * Fh) {
        const int b = (int)(idx >> 3), f = (int)(idx & 7);
        din[idx] = x[(size_t)b * XROW + (TIN - 1) * Fh + f];
    }
}

extern "C" void kernel_launch(void* const* d_in, const int* in_sizes, int n_in,
                              void* d_out, int out_size, void* d_ws, size_t ws_size,
                              hipStream_t stream)
{
    const float* x     = (const float*)d_in[0];
    const float* eWih0 = (const float*)d_in[1];
    const float* eWhh0 = (const float*)d_in[2];
    const float* ebih0 = (const float*)d_in[3];
    const float* ebhh0 = (const float*)d_in[4];
    const float* eWih1 = (const float*)d_in[5];
    const float* eWhh1 = (const float*)d_in[6];
    const float* ebih1 = (const float*)d_in[7];
    const float* ebhh1 = (const float*)d_in[8];
    const float* dWih  = (const float*)d_in[9];
    const float* dWhh  = (const float*)d_in[10];
    const float* dbih  = (const float*)d_in[11];
    const float* dbhh  = (const float*)d_in[12];
    const float* f1W   = (const float*)d_in[13];
    const float* f1b   = (const float*)d_in[14];
    const float* inW   = (const float*)d_in[15];
    const float* inb   = (const float*)d_in[16];
    const float* oW    = (const float*)d_in[17];
    const float* ob    = (const float*)d_in[18];
    const float* f2W   = (const float*)d_in[19];
    const float* f2b   = (const float*)d_in[20];
    float* out = (float*)d_out;
    float* ws  = (float*)d_ws;

    const size_t BH = (size_t)Bsz * H;  // 262144
    float* h0a  = ws;
    float* c0   = ws + 1 * BH;
    float* h1a  = ws + 2 * BH;
    float* c1   = ws + 3 * BH;
    float* h0b  = ws + 4 * BH;
    float* h1b  = ws + 5 * BH;
    float* dh0  = ws + 6 * BH;          // F*BH
    float* dh1  = dh0 + 8 * BH;
    float* dc   = dh1 + 8 * BH;
    float* abuf = dc + 8 * BH;          // fc1 out / out-proj out
    float* qkv  = abuf + 8 * BH;        // F*B*3H
    float* attn = qkv + 24 * BH;        // F*B*B
    float* av   = attn + 32 * BH;       // F*BH
    float* din  = av + 8 * BH;          // B*F

    // zero h0a,c0,h1a,c1 (contiguous 4*BH)
    hipMemsetAsync(ws, 0, 4 * BH * sizeof(float), stream);

    const dim3 blk(256);

    // ---------------- encoder ----------------
    for (int t = 0; t < TIN; ++t) {
        const float* hin0 = (t & 1) ? h0b : h0a;
        float*       hout0 = (t & 1) ? h0a : h0b;
        const float* hin1 = (t & 1) ? h1b : h1a;
        float*       hout1 = (t & 1) ? h1a : h1b;
        lstm_step_kernel<0><<<dim3(16, 16, 1), blk, 0, stream>>>(
            hin0, eWhh0, nullptr, nullptr, x + t * Fh, eWih0, ebih0, ebhh0, c0, hout0);
        lstm_step_kernel<1><<<dim3(16, 16, 1), blk, 0, stream>>>(
            hin1, eWhh1, hout0, eWih1, nullptr, nullptr, ebih1, ebhh1, c1, hout1);
    }
    // TIN even -> final states in h0a / h1a
    combine_init_kernel<<<dim3(1024), blk, 0, stream>>>(h0a, c0, h1a, c1, x, dh0, dc, din);

    // ---------------- decoder ----------------
    for (int t = 0; t < TOUT; ++t) {
        const float* dhin = (t & 1) ? dh1 : dh0;
        float*       dhout = (t & 1) ? dh0 : dh1;
        lstm_step_kernel<2><<<dim3(16, 16, 8), blk, 0, stream>>>(
            dhin, dWhh, nullptr, nullptr, din, dWih, dbih, dbhh, dc, dhout);
        // a = leaky(h2 @ f1W^T + f1b)
        gemm_kernel<0, 1><<<dim3(16, 4, 8), blk, 0, stream>>>(
            dhout, H, BH, f1W, H, (size_t)H * H, f1b, H, abuf, H, BH, H, 1.f);
        // qkv = a @ inW^T + inb
        gemm_kernel<0, 0><<<dim3(16, 12, 8), blk, 0, stream>>>(
            abuf, H, BH, inW, H, (size_t)(3 * H) * H, inb, 3 * H, qkv, 3 * H, 3 * BH, H, 1.f);
        // attn = (q @ k^T) * scale
        gemm_kernel<0, 2><<<dim3(16, 16, 8), blk, 0, stream>>>(
            qkv, 3 * H, 3 * BH, qkv + H, 3 * H, 3 * BH, nullptr, 0,
            attn, Bsz, 4 * BH, H, 0.0625f);
        softmax_kernel<<<dim3(Fh * Bsz), blk, 0, stream>>>(attn);
        // av = attn @ v   (v is (K=B, N=H) -> BT=1)
        gemm_kernel<1, 2><<<dim3(16, 4, 8), blk, 0, stream>>>(
            attn, Bsz, 4 * BH, qkv + 2 * H, 3 * H, 3 * BH, nullptr, 0,
            av, H, BH, Bsz, 1.f);
        // ao = av @ oW^T + ob  (reuse abuf)
        gemm_kernel<0, 0><<<dim3(16, 4, 8), blk, 0, stream>>>(
            av, H, BH, oW, H, (size_t)H * H, ob, H, abuf, H, BH, H, 1.f);
        fc2_out_kernel<<<dim3(Fh * Bsz / 4), blk, 0, stream>>>(abuf, f2W, f2b, out, din, t);
    }
    (void)in_sizes; (void)n_in; (void)out_size; (void)ws_size;
}

// Round 2
// 7805.416 us; speedup vs baseline: 1.9874x; 1.9874x over previous
//
#include <hip/hip_runtime.h>
#include <math.h>

#define H 256
#define H4 1024
#define Bsz 1024
#define TIN 168
#define TOUT 24
#define Fh 8
#define XROW (TIN*Fh)
#define BH ((size_t)Bsz * H)   // 262144

typedef __attribute__((ext_vector_type(8))) short bf16x8;
typedef __attribute__((ext_vector_type(4))) float f32x4;

__device__ __forceinline__ float sigmf(float x) { return 1.0f / (1.0f + expf(-x)); }

__device__ __forceinline__ ushort f2bf(float f) {
    union { float f; unsigned u; } v; v.f = f;
    unsigned r = v.u + 0x7fff + ((v.u >> 16) & 1);
    return (ushort)(r >> 16);
}
__device__ __forceinline__ float bf2f(ushort u) {
    union { unsigned u; float f; } v; v.u = ((unsigned)u) << 16;
    return v.f;
}

__global__ __launch_bounds__(256)
void cast_f32_bf16(const float* __restrict__ in, ushort* __restrict__ out, int n) {
    int i = blockIdx.x * 256 + threadIdx.x;
    const int stride = gridDim.x * 256;
    for (; i < n; i += stride) out[i] = f2bf(in[i]);
}

// ---------------------------------------------------------------------------
// Encoder step, both layers pipeline-skewed in one launch:
//   z=0: L0 computes step t      (needs t < TIN)
//   z=1: L1 computes step t-1    (needs t >= 1); consumes h0in (=ys0[t-1])
// Wave: 16 b-rows x 16 jj x 4 gates. WG = 4 waves on b (64 rows).
// Grid (16, 16, 2). All GEMM operands read directly from global (L2-resident).
// ---------------------------------------------------------------------------
__global__ __launch_bounds__(256)
void enc_step_mfma(const ushort* __restrict__ h0in, ushort* __restrict__ h0out,
                   const ushort* __restrict__ h1in, ushort* __restrict__ h1out,
                   const ushort* __restrict__ Whh0, const ushort* __restrict__ Wih1,
                   const ushort* __restrict__ Whh1,
                   const float* __restrict__ x, const float* __restrict__ Wih0,
                   const float* __restrict__ bih0, const float* __restrict__ bhh0,
                   const float* __restrict__ bih1, const float* __restrict__ bhh1,
                   float* __restrict__ c0, float* __restrict__ c1, int t)
{
    const int z = blockIdx.z;
    if (z == 0 && t >= TIN) return;
    if (z == 1 && t < 1) return;
    const int tid = threadIdx.x;
    const int l = tid & 63, w = tid >> 6;
    const int m0 = blockIdx.x * 64 + w * 16;
    const int jj0 = blockIdx.y * 16;
    const int lr = l & 15, lk = (l >> 4) * 8;

    const ushort* Ap  = (z == 0) ? h0in : h1in;
    const ushort* Wp  = (z == 0) ? Whh0 : Whh1;
    const float* bih  = (z == 0) ? bih0 : bih1;
    const float* bhh  = (z == 0) ? bhh0 : bhh1;
    float* cb         = (z == 0) ? c0 : c1;
    ushort* hout      = (z == 0) ? h0out : h1out;

    f32x4 acc[4] = {};
    {
        const ushort* Arow = Ap + (size_t)(m0 + lr) * H + lk;
        const ushort* Wrow = Wp + (size_t)(jj0 + lr) * H + lk;
        for (int ks = 0; ks < H; ks += 32) {
            bf16x8 af = *(const bf16x8*)(Arow + ks);
#pragma unroll
            for (int g = 0; g < 4; ++g) {
                bf16x8 bf = *(const bf16x8*)(Wrow + (size_t)g * (H * H) + ks);
                acc[g] = __builtin_amdgcn_mfma_f32_16x16x32_bf16(af, bf, acc[g], 0, 0, 0);
            }
        }
    }
    if (z == 1) {  // + ys0[t-1] @ Wih1^T
        const ushort* Arow = h0in + (size_t)(m0 + lr) * H + lk;
        const ushort* Wrow = Wih1 + (size_t)(jj0 + lr) * H + lk;
        for (int ks = 0; ks < H; ks += 32) {
            bf16x8 af = *(const bf16x8*)(Arow + ks);
#pragma unroll
            for (int g = 0; g < 4; ++g) {
                bf16x8 bf = *(const bf16x8*)(Wrow + (size_t)g * (H * H) + ks);
                acc[g] = __builtin_amdgcn_mfma_f32_16x16x32_bf16(af, bf, acc[g], 0, 0, 0);
            }
        }
    }

    const int jj = jj0 + lr;
    const int mb = m0 + (l >> 4) * 4;
#pragma unroll
    for (int r = 0; r < 4; ++r) {
        const int m = mb + r;
        float pre[4];
#pragma unroll
        for (int g = 0; g < 4; ++g)
            pre[g] = acc[g][r] + bih[g * H + jj] + bhh[g * H + jj];
        if (z == 0) {
            const float* xr = x + (size_t)m * XROW + t * Fh;
#pragma unroll
            for (int g = 0; g < 4; ++g) {
                const float* wr = Wih0 + (size_t)(g * H + jj) * Fh;
                float s = 0.f;
#pragma unroll
                for (int ki = 0; ki < Fh; ++ki) s = fmaf(xr[ki], wr[ki], s);
                pre[g] += s;
            }
        }
        const float ig = sigmf(pre[0]);
        const float fg = sigmf(pre[1]);
        const float gg = tanhf(pre[2]);
        const float og = sigmf(pre[3]);
        const size_t off = (size_t)m * H + jj;
        const float cn = fg * cb[off] + ig * gg;
        cb[off] = cn;
        hout[off] = f2bf(og * tanhf(cn));
    }
}

// ---------------------------------------------------------------------------
// Decoder LSTM step, batched over f (blockIdx.z). Same tiling as encoder.
// x-term is rank-1: din[b,f] * dWih[f, g*H+jj].
// ---------------------------------------------------------------------------
__global__ __launch_bounds__(256)
void dec_lstm_mfma(const ushort* __restrict__ dhin, ushort* __restrict__ dhout,
                   const ushort* __restrict__ Whh, const float* __restrict__ Wih,
                   const float* __restrict__ din, const float* __restrict__ bih,
                   const float* __restrict__ bhh, float* __restrict__ dc)
{
    const int f = blockIdx.z;
    const int tid = threadIdx.x;
    const int l = tid & 63, w = tid >> 6;
    const int m0 = blockIdx.x * 64 + w * 16;
    const int jj0 = blockIdx.y * 16;
    const int lr = l & 15, lk = (l >> 4) * 8;

    const ushort* Ap = dhin + (size_t)f * BH;
    const ushort* Wp = Whh + (size_t)f * (H4 * H);
    const float* bi = bih + f * H4;
    const float* bh = bhh + f * H4;
    const float* wx = Wih + f * H4;
    float* cb = dc + (size_t)f * BH;
    ushort* hout = dhout + (size_t)f * BH;

    f32x4 acc[4] = {};
    const ushort* Arow = Ap + (size_t)(m0 + lr) * H + lk;
    const ushort* Wrow = Wp + (size_t)(jj0 + lr) * H + lk;
    for (int ks = 0; ks < H; ks += 32) {
        bf16x8 af = *(const bf16x8*)(Arow + ks);
#pragma unroll
        for (int g = 0; g < 4; ++g) {
            bf16x8 bf = *(const bf16x8*)(Wrow + (size_t)g * (H * H) + ks);
            acc[g] = __builtin_amdgcn_mfma_f32_16x16x32_bf16(af, bf, acc[g], 0, 0, 0);
        }
    }

    const int jj = jj0 + lr;
    const int mb = m0 + (l >> 4) * 4;
#pragma unroll
    for (int r = 0; r < 4; ++r) {
        const int m = mb + r;
        const float xi = din[m * Fh + f];
        float pre[4];
#pragma unroll
        for (int g = 0; g < 4; ++g)
            pre[g] = acc[g][r] + bi[g * H + jj] + bh[g * H + jj] + xi * wx[g * H + jj];
        const float ig = sigmf(pre[0]);
        const float fg = sigmf(pre[1]);
        const float gg = tanhf(pre[2]);
        const float og = sigmf(pre[3]);
        const size_t off = (size_t)m * H + jj;
        const float cn = fg * cb[off] + ig * gg;
        cb[off] = cn;
        hout[off] = f2bf(og * tanhf(cn));
    }
}

// ---------------------------------------------------------------------------
// Generic bf16 MFMA GEMM: C = act(A @ W^T + bias), batched over blockIdx.z.
// A: (M,K) bf16 row-major (lda elems). W: (N,K) bf16 row-major (ldw elems).
// Wave: 16m x 64n. WG = 4 waves on m (64m x 64n).
// ACT 0: +bias, leaky -> bf16 out
// ACT 1: +bias; n<512 -> bf16 out (q,k; ldo); n>=512 -> transposed packed
//        store into out2 (vT, H x Bsz per z)
// ACT 2: *alpha -> bf16 out
// ACT 3: none   -> bf16 out
// ACT 4: +bias  -> f32 outf
// ---------------------------------------------------------------------------
template<int ACT>
__global__ __launch_bounds__(256)
void gemm_mfma(const ushort* __restrict__ A, int lda, size_t sA,
               const ushort* __restrict__ W, int ldw, size_t sW,
               const float* __restrict__ bias, int sb,
               ushort* __restrict__ out, int ldo, size_t sO,
               float* __restrict__ outf, ushort* __restrict__ out2,
               int K, float alpha)
{
    const int tid = threadIdx.x;
    const int l = tid & 63, w = tid >> 6;
    const int m0 = blockIdx.x * 64 + w * 16;
    const int n0 = blockIdx.y * 64;
    const int z = blockIdx.z;
    const int lr = l & 15, lk = (l >> 4) * 8;

    const ushort* Arow = A + (size_t)z * sA + (size_t)(m0 + lr) * lda + lk;
    const ushort* Wrow = W + (size_t)z * sW + (size_t)(n0 + lr) * ldw + lk;

    f32x4 acc[4] = {};
    for (int ks = 0; ks < K; ks += 32) {
        bf16x8 af = *(const bf16x8*)(Arow + ks);
#pragma unroll
        for (int nf = 0; nf < 4; ++nf) {
            bf16x8 bf = *(const bf16x8*)(Wrow + (size_t)nf * 16 * ldw + ks);
            acc[nf] = __builtin_amdgcn_mfma_f32_16x16x32_bf16(af, bf, acc[nf], 0, 0, 0);
        }
    }

    const int mb = m0 + (l >> 4) * 4;
#pragma unroll
    for (int nf = 0; nf < 4; ++nf) {
        const int n = n0 + nf * 16 + lr;
        if (ACT == 1 && (n0 + nf * 16) >= 512) {
            const float b4 = bias[z * sb + n];
            ushort4 pk;
            pk.x = f2bf(acc[nf][0] + b4);
            pk.y = f2bf(acc[nf][1] + b4);
            pk.z = f2bf(acc[nf][2] + b4);
            pk.w = f2bf(acc[nf][3] + b4);
            *(ushort4*)(out2 + (size_t)z * (H * Bsz) + (size_t)(n - 512) * Bsz + mb) = pk;
        } else {
#pragma unroll
            for (int r = 0; r < 4; ++r) {
                const int m = mb + r;
                float v = acc[nf][r];
                if (ACT == 0) {
                    v += bias[z * sb + n];
                    v = (v > 0.f) ? v : 0.01f * v;
                    out[(size_t)z * sO + (size_t)m * ldo + n] = f2bf(v);
                } else if (ACT == 1) {
                    v += bias[z * sb + n];
                    out[(size_t)z * sO + (size_t)m * ldo + n] = f2bf(v);
                } else if (ACT == 2) {
                    out[(size_t)z * sO + (size_t)m * ldo + n] = f2bf(v * alpha);
                } else if (ACT == 3) {
                    out[(size_t)z * sO + (size_t)m * ldo + n] = f2bf(v);
                } else {
                    v += bias[z * sb + n];
                    outf[(size_t)z * sO + (size_t)m * ldo + n] = v;
                }
            }
        }
    }
}

// Row softmax over 1024-wide bf16 rows (grid = F*B rows).
__global__ __launch_bounds__(256)
void softmax_bf16(ushort* __restrict__ attn)
{
    const size_t row = blockIdx.x;
    ushort* p = attn + row * Bsz;
    const int tid = threadIdx.x;
    ushort4 u = *(const ushort4*)(p + tid * 4);
    float v0 = bf2f(u.x), v1 = bf2f(u.y), v2 = bf2f(u.z), v3 = bf2f(u.w);
    float m = fmaxf(fmaxf(v0, v1), fmaxf(v2, v3));
#pragma unroll
    for (int s = 1; s < 64; s <<= 1) m = fmaxf(m, __shfl_xor(m, s));
    __shared__ float red[4];
    __shared__ float red2[4];
    if ((tid & 63) == 0) red[tid >> 6] = m;
    __syncthreads();
    m = fmaxf(fmaxf(red[0], red[1]), fmaxf(red[2], red[3]));
    v0 = expf(v0 - m); v1 = expf(v1 - m); v2 = expf(v2 - m); v3 = expf(v3 - m);
    float s4 = v0 + v1 + v2 + v3;
#pragma unroll
    for (int s = 1; s < 64; s <<= 1) s4 += __shfl_xor(s4, s);
    if ((tid & 63) == 0) red2[tid >> 6] = s4;
    __syncthreads();
    const float inv = 1.0f / (red2[0] + red2[1] + red2[2] + red2[3]);
    u.x = f2bf(v0 * inv); u.y = f2bf(v1 * inv); u.z = f2bf(v2 * inv); u.w = f2bf(v3 * inv);
    *(ushort4*)(p + tid * 4) = u;
}

// fc2 + leaky + write out[:, t, :] and feed back din. One wave per (f,b) row.
__global__ __launch_bounds__(256)
void fc2_out_kernel(const float* __restrict__ ao, const float* __restrict__ f2W,
                    const float* __restrict__ f2b, float* __restrict__ out,
                    float* __restrict__ din, int t)
{
    const int tid = threadIdx.x;
    const int lane = tid & 63, w = tid >> 6;
    const size_t idx = (size_t)blockIdx.x * 4 + w;  // 0..F*B-1
    const int f = (int)(idx >> 10), b = (int)(idx & 1023);
    const float* row = ao + ((size_t)f * Bsz + b) * H;
    const float4 v = ((const float4*)row)[lane];
    const float4 wv = ((const float4*)(f2W + f * H))[lane];
    float s = v.x * wv.x + v.y * wv.y + v.z * wv.z + v.w * wv.w;
#pragma unroll
    for (int d = 1; d < 64; d <<= 1) s += __shfl_xor(s, d);
    if (lane == 0) {
        s += f2b[f];
        s = (s > 0.f) ? s : 0.01f * s;
        out[(size_t)b * (TOUT * Fh) + (size_t)t * Fh + f] = s;
        din[b * Fh + f] = s;
    }
}

// (h0+h1)/2, (c0+c1)/2 broadcast to all F decoder states; din = x[:,-1,:].
__global__ __launch_bounds__(256)
void combine_init_bf16(const ushort* __restrict__ h0, const float* __restrict__ c0,
                       const ushort* __restrict__ h1, const float* __restrict__ c1,
                       const float* __restrict__ x,
                       ushort* __restrict__ dh, float* __restrict__ dcbuf,
                       float* __restrict__ din)
{
    const size_t idx = (size_t)blockIdx.x * 256 + threadIdx.x;  // 0..B*H-1
    const float hm = 0.5f * (bf2f(h0[idx]) + bf2f(h1[idx]));
    const float cm = 0.5f * (c0[idx] + c1[idx]);
    const ushort hb = f2bf(hm);
#pragma unroll
    for (int f = 0; f < Fh; ++f) { dh[f * BH + idx] = hb; dcbuf[f * BH + idx] = cm; }
    if (idx < (size_t)Bsz * Fh) {
        const int b = (int)(idx >> 3), f = (int)(idx & 7);
        din[idx] = x[(size_t)b * XROW + (TIN - 1) * Fh + f];
    }
}

extern "C" void kernel_launch(void* const* d_in, const int* in_sizes, int n_in,
                              void* d_out, int out_size, void* d_ws, size_t ws_size,
                              hipStream_t stream)
{
    const float* x     = (const float*)d_in[0];
    const float* eWih0 = (const float*)d_in[1];
    const float* eWhh0 = (const float*)d_in[2];
    const float* ebih0 = (const float*)d_in[3];
    const float* ebhh0 = (const float*)d_in[4];
    const float* eWih1 = (const float*)d_in[5];
    const float* eWhh1 = (const float*)d_in[6];
    const float* ebih1 = (const float*)d_in[7];
    const float* ebhh1 = (const float*)d_in[8];
    const float* dWih  = (const float*)d_in[9];
    const float* dWhh  = (const float*)d_in[10];
    const float* dbih  = (const float*)d_in[11];
    const float* dbhh  = (const float*)d_in[12];
    const float* f1W   = (const float*)d_in[13];
    const float* f1b   = (const float*)d_in[14];
    const float* inW   = (const float*)d_in[15];
    const float* inb   = (const float*)d_in[16];
    const float* oW    = (const float*)d_in[17];
    const float* ob    = (const float*)d_in[18];
    const float* f2W   = (const float*)d_in[19];
    const float* f2b   = (const float*)d_in[20];
    float* out = (float*)d_out;

    // ---- workspace layout (byte offsets, 256-aligned) ----
    char* base = (char*)d_ws;
    size_t o = 0;
    auto alloc = [&](size_t bytes) { void* p = base + o; o += (bytes + 255) & ~(size_t)255; return p; };
    float*  c0   = (float*)alloc(BH * 4);
    float*  c1   = (float*)alloc(BH * 4);
    ushort* h0a  = (ushort*)alloc(BH * 2);
    ushort* h1a  = (ushort*)alloc(BH * 2);
    ushort* h0b  = (ushort*)alloc(BH * 2);
    ushort* h1b  = (ushort*)alloc(BH * 2);
    ushort* dh0  = (ushort*)alloc(8 * BH * 2);
    ushort* dh1  = (ushort*)alloc(8 * BH * 2);
    float*  dc   = (float*)alloc(8 * BH * 4);
    ushort* a_bf = (ushort*)alloc(8 * BH * 2);
    ushort* qk_bf= (ushort*)alloc((size_t)8 * Bsz * 512 * 2);
    ushort* vT   = (ushort*)alloc((size_t)8 * H * Bsz * 2);
    ushort* attn = (ushort*)alloc((size_t)8 * Bsz * Bsz * 2);
    ushort* av_bf= (ushort*)alloc(8 * BH * 2);
    float*  ao   = (float*)alloc(8 * BH * 4);
    float*  din  = (float*)alloc((size_t)Bsz * Fh * 4);
    // bf16 weight copies
    ushort* wWhh0 = (ushort*)alloc((size_t)H4 * H * 2);
    ushort* wWih1 = (ushort*)alloc((size_t)H4 * H * 2);
    ushort* wWhh1 = (ushort*)alloc((size_t)H4 * H * 2);
    ushort* wdWhh = (ushort*)alloc((size_t)8 * H4 * H * 2);
    ushort* wf1W  = (ushort*)alloc((size_t)8 * H * H * 2);
    ushort* winW  = (ushort*)alloc((size_t)8 * 3 * H * H * 2);
    ushort* woW   = (ushort*)alloc((size_t)8 * H * H * 2);

    const dim3 blk(256);

    // zero c0,c1,h0a,h1a (contiguous at ws start: 1M+1M+512K+512K bytes)
    hipMemsetAsync(d_ws, 0, BH * 4 * 2 + BH * 2 * 2, stream);

    // ---- cast weights to bf16 ----
    cast_f32_bf16<<<dim3(512), blk, 0, stream>>>(eWhh0, wWhh0, H4 * H);
    cast_f32_bf16<<<dim3(512), blk, 0, stream>>>(eWih1, wWih1, H4 * H);
    cast_f32_bf16<<<dim3(512), blk, 0, stream>>>(eWhh1, wWhh1, H4 * H);
    cast_f32_bf16<<<dim3(1024), blk, 0, stream>>>(dWhh, wdWhh, 8 * H4 * H);
    cast_f32_bf16<<<dim3(512), blk, 0, stream>>>(f1W, wf1W, 8 * H * H);
    cast_f32_bf16<<<dim3(1024), blk, 0, stream>>>(inW, winW, 8 * 3 * H * H);
    cast_f32_bf16<<<dim3(512), blk, 0, stream>>>(oW, woW, 8 * H * H);

    // ---- encoder: 169 pipeline-skewed launches ----
    for (int i = 0; i <= TIN; ++i) {
        const int p = i & 1;
        const ushort* h0in = p ? h0b : h0a;
        ushort*       h0out = p ? h0a : h0b;
        const ushort* h1in = p ? h1a : h1b;
        ushort*       h1out = p ? h1b : h1a;
        enc_step_mfma<<<dim3(16, 16, 2), blk, 0, stream>>>(
            h0in, h0out, h1in, h1out, wWhh0, wWih1, wWhh1,
            x, eWih0, ebih0, ebhh0, ebih1, ebhh1, c0, c1, i);
    }
    // final states: h0 in h0a (written at i=167, p=1), h1 in h1a (i=168, p=0)
    combine_init_bf16<<<dim3(1024), blk, 0, stream>>>(h0a, c0, h1a, c1, x, dh0, dc, din);

    // ---- decoder ----
    for (int t = 0; t < TOUT; ++t) {
        const ushort* dhin = (t & 1) ? dh1 : dh0;
        ushort*       dhout = (t & 1) ? dh0 : dh1;
        dec_lstm_mfma<<<dim3(16, 16, 8), blk, 0, stream>>>(
            dhin, dhout, wdWhh, dWih, din, dbih, dbhh, dc);
        // a = leaky(h2 @ f1W^T + f1b)
        gemm_mfma<0><<<dim3(16, 4, 8), blk, 0, stream>>>(
            dhout, H, BH, wf1W, H, (size_t)H * H, f1b, H,
            a_bf, H, BH, nullptr, nullptr, H, 1.f);
        // qkv = a @ inW^T + inb ; q,k -> qk_bf (ld 512), v -> vT (transposed)
        gemm_mfma<1><<<dim3(16, 12, 8), blk, 0, stream>>>(
            a_bf, H, BH, winW, H, (size_t)3 * H * H, inb, 3 * H,
            qk_bf, 512, (size_t)Bsz * 512, nullptr, vT, H, 1.f);
        // attn = (q @ k^T) * scale
        gemm_mfma<2><<<dim3(16, 16, 8), blk, 0, stream>>>(
            qk_bf, 512, (size_t)Bsz * 512, qk_bf + H, 512, (size_t)Bsz * 512,
            nullptr, 0, attn, Bsz, (size_t)Bsz * Bsz, nullptr, nullptr, H, 0.0625f);
        softmax_bf16<<<dim3(Fh * Bsz), blk, 0, stream>>>(attn);
        // av = attn @ v  (W = vT: (N=H, K=B) row-major)
        gemm_mfma<3><<<dim3(16, 4, 8), blk, 0, stream>>>(
            attn, Bsz, (size_t)Bsz * Bsz, vT, Bsz, (size_t)H * Bsz,
            nullptr, 0, av_bf, H, BH, nullptr, nullptr, Bsz, 1.f);
        // ao = av @ oW^T + ob  (f32 out for fc2)
        gemm_mfma<4><<<dim3(16, 4, 8), blk, 0, stream>>>(
            av_bf, H, BH, woW, H, (size_t)H * H, ob, H,
            nullptr, H, BH, ao, nullptr, H, 1.f);
        fc2_out_kernel<<<dim3(Fh * Bsz / 4), blk, 0, stream>>>(ao, f2W, f2b, out, din, t);
    }
    (void)in_sizes; (void)n_in; (void)out_size; (void)ws_size; (void)ebih0;
}

// Round 3
// 5627.328 us; speedup vs baseline: 2.7567x; 1.3871x over previous
//
#include <hip/hip_runtime.h>
#include <math.h>

#define H 256
#define H4 1024
#define Bsz 1024
#define TIN 168
#define TOUT 24
#define Fh 8
#define XROW (TIN*Fh)
#define BH ((size_t)Bsz * H)   // 262144

typedef __attribute__((ext_vector_type(8))) short bf16x8;
typedef __attribute__((ext_vector_type(4))) float f32x4;

__device__ __forceinline__ float sigmf(float x) { return 1.0f / (1.0f + expf(-x)); }

__device__ __forceinline__ ushort f2bf(float f) {
    union { float f; unsigned u; } v; v.f = f;
    unsigned r = v.u + 0x7fff + ((v.u >> 16) & 1);
    return (ushort)(r >> 16);
}
__device__ __forceinline__ float bf2f(ushort u) {
    union { unsigned u; float f; } v; v.u = ((unsigned)u) << 16;
    return v.f;
}

__global__ __launch_bounds__(256)
void cast_f32_bf16(const float* __restrict__ in, ushort* __restrict__ out, int n) {
    int i = blockIdx.x * 256 + threadIdx.x;
    const int stride = gridDim.x * 256;
    for (; i < n; i += stride) out[i] = f2bf(in[i]);
}

// ---------------------------------------------------------------------------
// Encoder step, both layers pipeline-skewed in one launch (unchanged, verified)
// ---------------------------------------------------------------------------
__global__ __launch_bounds__(256)
void enc_step_mfma(const ushort* __restrict__ h0in, ushort* __restrict__ h0out,
                   const ushort* __restrict__ h1in, ushort* __restrict__ h1out,
                   const ushort* __restrict__ Whh0, const ushort* __restrict__ Wih1,
                   const ushort* __restrict__ Whh1,
                   const float* __restrict__ x, const float* __restrict__ Wih0,
                   const float* __restrict__ bih0, const float* __restrict__ bhh0,
                   const float* __restrict__ bih1, const float* __restrict__ bhh1,
                   float* __restrict__ c0, float* __restrict__ c1, int t)
{
    const int z = blockIdx.z;
    if (z == 0 && t >= TIN) return;
    if (z == 1 && t < 1) return;
    const int tid = threadIdx.x;
    const int l = tid & 63, w = tid >> 6;
    const int m0 = blockIdx.x * 64 + w * 16;
    const int jj0 = blockIdx.y * 16;
    const int lr = l & 15, lk = (l >> 4) * 8;

    const ushort* Ap  = (z == 0) ? h0in : h1in;
    const ushort* Wp  = (z == 0) ? Whh0 : Whh1;
    const float* bih  = (z == 0) ? bih0 : bih1;
    const float* bhh  = (z == 0) ? bhh0 : bhh1;
    float* cb         = (z == 0) ? c0 : c1;
    ushort* hout      = (z == 0) ? h0out : h1out;

    f32x4 acc[4] = {};
    {
        const ushort* Arow = Ap + (size_t)(m0 + lr) * H + lk;
        const ushort* Wrow = Wp + (size_t)(jj0 + lr) * H + lk;
        for (int ks = 0; ks < H; ks += 32) {
            bf16x8 af = *(const bf16x8*)(Arow + ks);
#pragma unroll
            for (int g = 0; g < 4; ++g) {
                bf16x8 bf = *(const bf16x8*)(Wrow + (size_t)g * (H * H) + ks);
                acc[g] = __builtin_amdgcn_mfma_f32_16x16x32_bf16(af, bf, acc[g], 0, 0, 0);
            }
        }
    }
    if (z == 1) {  // + ys0[t-1] @ Wih1^T
        const ushort* Arow = h0in + (size_t)(m0 + lr) * H + lk;
        const ushort* Wrow = Wih1 + (size_t)(jj0 + lr) * H + lk;
        for (int ks = 0; ks < H; ks += 32) {
            bf16x8 af = *(const bf16x8*)(Arow + ks);
#pragma unroll
            for (int g = 0; g < 4; ++g) {
                bf16x8 bf = *(const bf16x8*)(Wrow + (size_t)g * (H * H) + ks);
                acc[g] = __builtin_amdgcn_mfma_f32_16x16x32_bf16(af, bf, acc[g], 0, 0, 0);
            }
        }
    }

    const int jj = jj0 + lr;
    const int mb = m0 + (l >> 4) * 4;
#pragma unroll
    for (int r = 0; r < 4; ++r) {
        const int m = mb + r;
        float pre[4];
#pragma unroll
        for (int g = 0; g < 4; ++g)
            pre[g] = acc[g][r] + bih[g * H + jj] + bhh[g * H + jj];
        if (z == 0) {
            const float* xr = x + (size_t)m * XROW + t * Fh;
#pragma unroll
            for (int g = 0; g < 4; ++g) {
                const float* wr = Wih0 + (size_t)(g * H + jj) * Fh;
                float s = 0.f;
#pragma unroll
                for (int ki = 0; ki < Fh; ++ki) s = fmaf(xr[ki], wr[ki], s);
                pre[g] += s;
            }
        }
        const float ig = sigmf(pre[0]);
        const float fg = sigmf(pre[1]);
        const float gg = tanhf(pre[2]);
        const float og = sigmf(pre[3]);
        const size_t off = (size_t)m * H + jj;
        const float cn = fg * cb[off] + ig * gg;
        cb[off] = cn;
        hout[off] = f2bf(og * tanhf(cn));
    }
}

// ---------------------------------------------------------------------------
// Precompute (once): w[f]=f2W@oW; u[f]=inW_v^T@w; d[f]=inb_v.w; cc[f]=ob.f2W+f2b
// ---------------------------------------------------------------------------
__global__ __launch_bounds__(256)
void precompute_kernel(const float* __restrict__ oW, const float* __restrict__ ob,
                       const float* __restrict__ f2W, const float* __restrict__ f2b,
                       const float* __restrict__ inW, const float* __restrict__ inb,
                       float* __restrict__ u, float* __restrict__ dconst,
                       float* __restrict__ ccv)
{
    __shared__ float wsh[256];
    const int f = blockIdx.x;
    const int tid = threadIdx.x;
    float s = 0.f;
    for (int i = 0; i < 256; ++i)
        s += f2W[f * 256 + i] * oW[(size_t)f * 65536 + (size_t)i * 256 + tid];
    wsh[tid] = s;
    __syncthreads();
    float su = 0.f;
    for (int n = 0; n < 256; ++n)
        su += wsh[n] * inW[(size_t)f * 768 * 256 + (size_t)(512 + n) * 256 + tid];
    u[f * 256 + tid] = su;
    if (tid == 0) {
        float dd = 0.f, cc = 0.f;
        for (int n = 0; n < 256; ++n) dd += wsh[n] * inb[f * 768 + 512 + n];
        for (int i = 0; i < 256; ++i) cc += ob[f * 256 + i] * f2W[f * 256 + i];
        dconst[f] = dd;
        ccv[f] = cc + f2b[f];
    }
}

// ---------------------------------------------------------------------------
// dec_fused: LSTM step + fc1 + q,k projection + vw, per 32-row block x f.
// grid 256 WGs (f = bid&7 for XCD-L2 weight locality), 256 threads (4 waves).
// Wave: rows (w&1)*16, col-half (w>>1).
// ---------------------------------------------------------------------------
__global__ __launch_bounds__(256)
void dec_fused(const ushort* __restrict__ dhin, ushort* __restrict__ dhout,
               const ushort* __restrict__ Whh, const float* __restrict__ Wih,
               const float* __restrict__ din, const float* __restrict__ bih,
               const float* __restrict__ bhh, float* __restrict__ dc,
               const ushort* __restrict__ f1Wb, const float* __restrict__ f1b,
               const ushort* __restrict__ inWb, const float* __restrict__ inb,
               const float* __restrict__ u, const float* __restrict__ dconst,
               ushort* __restrict__ qbuf, ushort* __restrict__ kbuf,
               float* __restrict__ vw)
{
    __shared__ ushort h2s[32][264];
    __shared__ ushort as[32][264];
    const int bid = blockIdx.x;
    const int f = bid & 7, mb = bid >> 3;
    const int m0 = mb * 32;
    const int tid = threadIdx.x;
    const int l = tid & 63, w = tid >> 6;
    const int lr = l & 15, lq = l >> 4, lk = lq * 8;
    const int rloc = (w & 1) * 16;
    const int ch = w >> 1;

    // ---- LSTM gates: 32 rows x 256 units (4 gates each), K=256 ----
    bf16x8 af[8];
    {
        const ushort* hrow = dhin + ((size_t)f * Bsz + m0 + rloc + lr) * H + lk;
#pragma unroll
        for (int ks = 0; ks < 8; ++ks) af[ks] = *(const bf16x8*)(hrow + ks * 32);
    }
    const ushort* Wbase = Whh + (size_t)f * (H4 * H);
    const float* bi = bih + f * H4;
    const float* bh = bhh + f * H4;
    const float* wx = Wih + f * H4;
    float* cb = dc + (size_t)f * BH;
    ushort* hog = dhout + (size_t)f * BH;

    for (int jf = 0; jf < 8; ++jf) {
        const int j0 = ch * 128 + jf * 16;
        f32x4 acc[4] = {};
#pragma unroll
        for (int g = 0; g < 4; ++g) {
            const ushort* wr = Wbase + (size_t)(g * H + j0 + lr) * H + lk;
#pragma unroll
            for (int ks = 0; ks < 8; ++ks) {
                bf16x8 bf = *(const bf16x8*)(wr + ks * 32);
                acc[g] = __builtin_amdgcn_mfma_f32_16x16x32_bf16(af[ks], bf, acc[g], 0, 0, 0);
            }
        }
        const int j = j0 + lr;
#pragma unroll
        for (int r = 0; r < 4; ++r) {
            const int mloc = rloc + lq * 4 + r;
            const int m = m0 + mloc;
            const float xi = din[m * Fh + f];
            float pre[4];
#pragma unroll
            for (int g = 0; g < 4; ++g)
                pre[g] = acc[g][r] + bi[g * H + j] + bh[g * H + j] + xi * wx[g * H + j];
            const float ig = sigmf(pre[0]);
            const float fg = sigmf(pre[1]);
            const float gg = tanhf(pre[2]);
            const float og = sigmf(pre[3]);
            const size_t off = (size_t)m * H + j;
            const float cn = fg * cb[off] + ig * gg;
            cb[off] = cn;
            const ushort hb = f2bf(og * tanhf(cn));
            hog[off] = hb;
            h2s[mloc][j] = hb;
        }
    }
    __syncthreads();

    // ---- fc1: a = leaky(h2 @ f1W^T + f1b), 32 x 256 ----
    {
        const ushort* Wf = f1Wb + (size_t)f * H * H;
#pragma unroll 2
        for (int cf = 0; cf < 8; ++cf) {
            const int n0 = ch * 128 + cf * 16;
            f32x4 acc = {};
#pragma unroll
            for (int ks = 0; ks < 8; ++ks) {
                bf16x8 a8 = *(const bf16x8*)&h2s[rloc + lr][ks * 32 + lk];
                bf16x8 b8 = *(const bf16x8*)(Wf + (size_t)(n0 + lr) * H + ks * 32 + lk);
                acc = __builtin_amdgcn_mfma_f32_16x16x32_bf16(a8, b8, acc, 0, 0, 0);
            }
            const int n = n0 + lr;
            const float bv = f1b[f * H + n];
#pragma unroll
            for (int r = 0; r < 4; ++r) {
                float v = acc[r] + bv;
                v = (v > 0.f) ? v : 0.01f * v;
                as[rloc + lq * 4 + r][n] = f2bf(v);
            }
        }
    }
    __syncthreads();

    // ---- qk: q = (a@inW_q^T + b)*scale, k = a@inW_k^T + b, 32 x 512 ----
    {
        const ushort* Wi = inWb + (size_t)f * 768 * H;
#pragma unroll 4
        for (int cf = 0; cf < 16; ++cf) {
            const int n0 = ch * 256 + cf * 16;
            f32x4 acc = {};
#pragma unroll
            for (int ks = 0; ks < 8; ++ks) {
                bf16x8 a8 = *(const bf16x8*)&as[rloc + lr][ks * 32 + lk];
                bf16x8 b8 = *(const bf16x8*)(Wi + (size_t)(n0 + lr) * H + ks * 32 + lk);
                acc = __builtin_amdgcn_mfma_f32_16x16x32_bf16(a8, b8, acc, 0, 0, 0);
            }
            const int n = n0 + lr;
            const float bv = inb[f * 768 + n];
#pragma unroll
            for (int r = 0; r < 4; ++r) {
                const float v = acc[r] + bv;
                const int m = m0 + rloc + lq * 4 + r;
                if (n0 < 256)
                    qbuf[((size_t)f * Bsz + m) * H + n] = f2bf(v * 0.0625f);
                else
                    kbuf[((size_t)f * Bsz + m) * H + (n - 256)] = f2bf(v);
            }
        }
    }

    // ---- vw[m] = a[m].u[f] + d[f] (8 rows per wave) ----
    const float4 u4 = *(const float4*)(u + f * H + l * 4);
#pragma unroll
    for (int rr = 0; rr < 8; ++rr) {
        const int mloc = w * 8 + rr;
        const ushort4 a4 = *(const ushort4*)&as[mloc][l * 4];
        float s = bf2f(a4.x) * u4.x + bf2f(a4.y) * u4.y
                + bf2f(a4.z) * u4.z + bf2f(a4.w) * u4.w;
#pragma unroll
        for (int d = 1; d < 64; d <<= 1) s += __shfl_xor(s, d);
        if (l == 0) vw[f * Bsz + m0 + mloc] = s + dconst[f];
    }
}

// ---------------------------------------------------------------------------
// attn_fused: scores (mfma(k,q) -> lane owns one q-row) + online softmax with
// scalar values vw + epilogue leaky(out+cc) -> out[b,t,f], din[b,f].
// grid 512 WGs (f = bid&7, 16 q-rows each), 4 waves = 4 k-quarters.
// ---------------------------------------------------------------------------
__global__ __launch_bounds__(256)
void attn_fused(const ushort* __restrict__ qbuf, const ushort* __restrict__ kbuf,
                const float* __restrict__ vw, const float* __restrict__ ccv,
                float* __restrict__ out, float* __restrict__ din, int t)
{
    __shared__ float tri[4][16][4];
    const int bid = blockIdx.x;
    const int f = bid & 7, qb = bid >> 3;
    const int q0 = qb * 16;
    const int tid = threadIdx.x;
    const int l = tid & 63, w = tid >> 6;
    const int lr = l & 15, lq = l >> 4, lk = lq * 8;

    bf16x8 qf[8];
    {
        const ushort* qrow = qbuf + ((size_t)f * Bsz + q0 + lr) * H + lk;
#pragma unroll
        for (int ks = 0; ks < 8; ++ks) qf[ks] = *(const bf16x8*)(qrow + ks * 32);
    }

    float mM = -1e30f, lS = 0.f, oS = 0.f;
    const int kb0 = w * 256;
    for (int kf = 0; kf < 16; ++kf) {
        const int kb = kb0 + kf * 16;
        const ushort* krow = kbuf + ((size_t)f * Bsz + kb + lr) * H + lk;
        f32x4 acc = {};
#pragma unroll
        for (int ks = 0; ks < 8; ++ks) {
            bf16x8 k8 = *(const bf16x8*)(krow + ks * 32);
            acc = __builtin_amdgcn_mfma_f32_16x16x32_bf16(k8, qf[ks], acc, 0, 0, 0);
        }
        const float4 v4 = *(const float4*)(vw + f * Bsz + kb + lq * 4);
        const float mx = fmaxf(fmaxf(acc[0], acc[1]), fmaxf(acc[2], acc[3]));
        const float mn = fmaxf(mM, mx);
        const float sc = __expf(mM - mn);
        const float e0 = __expf(acc[0] - mn), e1 = __expf(acc[1] - mn);
        const float e2 = __expf(acc[2] - mn), e3 = __expf(acc[3] - mn);
        lS = lS * sc + (e0 + e1 + e2 + e3);
        oS = oS * sc + (e0 * v4.x + e1 * v4.y + e2 * v4.z + e3 * v4.w);
        mM = mn;
    }
#pragma unroll
    for (int d = 16; d < 64; d <<= 1) {
        const float m2 = __shfl_xor(mM, d), l2 = __shfl_xor(lS, d), o2 = __shfl_xor(oS, d);
        const float mn = fmaxf(mM, m2);
        const float sa = __expf(mM - mn), sb = __expf(m2 - mn);
        lS = lS * sa + l2 * sb;
        oS = oS * sa + o2 * sb;
        mM = mn;
    }
    if (l < 16) { tri[w][l][0] = mM; tri[w][l][1] = lS; tri[w][l][2] = oS; }
    __syncthreads();
    if (tid < 16) {
        float M = tri[0][tid][0], L = tri[0][tid][1], O = tri[0][tid][2];
#pragma unroll
        for (int ww = 1; ww < 4; ++ww) {
            const float m2 = tri[ww][tid][0], l2 = tri[ww][tid][1], o2 = tri[ww][tid][2];
            const float mn = fmaxf(M, m2);
            const float sa = __expf(M - mn), sb = __expf(m2 - mn);
            L = L * sa + l2 * sb;
            O = O * sa + o2 * sb;
            M = mn;
        }
        float val = O / L + ccv[f];
        val = (val > 0.f) ? val : 0.01f * val;
        const int b = q0 + tid;
        out[(size_t)b * (TOUT * Fh) + (size_t)t * Fh + f] = val;
        din[b * Fh + f] = val;
    }
}

// (h0+h1)/2, (c0+c1)/2 broadcast to all F decoder states; din = x[:,-1,:].
__global__ __launch_bounds__(256)
void combine_init_bf16(const ushort* __restrict__ h0, const float* __restrict__ c0,
                       const ushort* __restrict__ h1, const float* __restrict__ c1,
                       const float* __restrict__ x,
                       ushort* __restrict__ dh, float* __restrict__ dcbuf,
                       float* __restrict__ din)
{
    const size_t idx = (size_t)blockIdx.x * 256 + threadIdx.x;  // 0..B*H-1
    const float hm = 0.5f * (bf2f(h0[idx]) + bf2f(h1[idx]));
    const float cm = 0.5f * (c0[idx] + c1[idx]);
    const ushort hb = f2bf(hm);
#pragma unroll
    for (int f = 0; f < Fh; ++f) { dh[f * BH + idx] = hb; dcbuf[f * BH + idx] = cm; }
    if (idx < (size_t)Bsz * Fh) {
        const int b = (int)(idx >> 3), f = (int)(idx & 7);
        din[idx] = x[(size_t)b * XROW + (TIN - 1) * Fh + f];
    }
}

extern "C" void kernel_launch(void* const* d_in, const int* in_sizes, int n_in,
                              void* d_out, int out_size, void* d_ws, size_t ws_size,
                              hipStream_t stream)
{
    const float* x     = (const float*)d_in[0];
    const float* eWih0 = (const float*)d_in[1];
    const float* eWhh0 = (const float*)d_in[2];
    const float* ebih0 = (const float*)d_in[3];
    const float* ebhh0 = (const float*)d_in[4];
    const float* eWih1 = (const float*)d_in[5];
    const float* eWhh1 = (const float*)d_in[6];
    const float* ebih1 = (const float*)d_in[7];
    const float* ebhh1 = (const float*)d_in[8];
    const float* dWih  = (const float*)d_in[9];
    const float* dWhh  = (const float*)d_in[10];
    const float* dbih  = (const float*)d_in[11];
    const float* dbhh  = (const float*)d_in[12];
    const float* f1W   = (const float*)d_in[13];
    const float* f1b   = (const float*)d_in[14];
    const float* inW   = (const float*)d_in[15];
    const float* inb   = (const float*)d_in[16];
    const float* oW    = (const float*)d_in[17];
    const float* ob    = (const float*)d_in[18];
    const float* f2W   = (const float*)d_in[19];
    const float* f2b   = (const float*)d_in[20];
    float* out = (float*)d_out;

    // ---- workspace layout ----
    char* base = (char*)d_ws;
    size_t o = 0;
    auto alloc = [&](size_t bytes) { void* p = base + o; o += (bytes + 255) & ~(size_t)255; return p; };
    float*  c0   = (float*)alloc(BH * 4);
    float*  c1   = (float*)alloc(BH * 4);
    ushort* h0a  = (ushort*)alloc(BH * 2);
    ushort* h1a  = (ushort*)alloc(BH * 2);
    ushort* h0b  = (ushort*)alloc(BH * 2);
    ushort* h1b  = (ushort*)alloc(BH * 2);
    ushort* dh0  = (ushort*)alloc(8 * BH * 2);
    ushort* dh1  = (ushort*)alloc(8 * BH * 2);
    float*  dc   = (float*)alloc(8 * BH * 4);
    ushort* qbuf = (ushort*)alloc(8 * BH * 2);
    ushort* kbuf = (ushort*)alloc(8 * BH * 2);
    float*  vwb  = (float*)alloc((size_t)Fh * Bsz * 4);
    float*  din  = (float*)alloc((size_t)Bsz * Fh * 4);
    float*  ubuf = (float*)alloc((size_t)Fh * H * 4);
    float*  dbuf = (float*)alloc(Fh * 4);
    float*  ccb  = (float*)alloc(Fh * 4);
    ushort* wWhh0 = (ushort*)alloc((size_t)H4 * H * 2);
    ushort* wWih1 = (ushort*)alloc((size_t)H4 * H * 2);
    ushort* wWhh1 = (ushort*)alloc((size_t)H4 * H * 2);
    ushort* wdWhh = (ushort*)alloc((size_t)8 * H4 * H * 2);
    ushort* wf1W  = (ushort*)alloc((size_t)8 * H * H * 2);
    ushort* winW  = (ushort*)alloc((size_t)8 * 768 * H * 2);

    const dim3 blk(256);

    // zero c0,c1,h0a,h1a (contiguous at ws start)
    hipMemsetAsync(d_ws, 0, BH * 4 * 2 + BH * 2 * 2, stream);

    // ---- weight casts + precompute ----
    cast_f32_bf16<<<dim3(512), blk, 0, stream>>>(eWhh0, wWhh0, H4 * H);
    cast_f32_bf16<<<dim3(512), blk, 0, stream>>>(eWih1, wWih1, H4 * H);
    cast_f32_bf16<<<dim3(512), blk, 0, stream>>>(eWhh1, wWhh1, H4 * H);
    cast_f32_bf16<<<dim3(1024), blk, 0, stream>>>(dWhh, wdWhh, 8 * H4 * H);
    cast_f32_bf16<<<dim3(512), blk, 0, stream>>>(f1W, wf1W, 8 * H * H);
    cast_f32_bf16<<<dim3(1024), blk, 0, stream>>>(inW, winW, 8 * 768 * H);
    precompute_kernel<<<dim3(8), blk, 0, stream>>>(oW, ob, f2W, f2b, inW, inb,
                                                   ubuf, dbuf, ccb);

    // ---- encoder: 169 pipeline-skewed launches ----
    for (int i = 0; i <= TIN; ++i) {
        const int p = i & 1;
        const ushort* h0in = p ? h0b : h0a;
        ushort*       h0out = p ? h0a : h0b;
        const ushort* h1in = p ? h1a : h1b;
        ushort*       h1out = p ? h1b : h1a;
        enc_step_mfma<<<dim3(16, 16, 2), blk, 0, stream>>>(
            h0in, h0out, h1in, h1out, wWhh0, wWih1, wWhh1,
            x, eWih0, ebih0, ebhh0, ebih1, ebhh1, c0, c1, i);
    }
    combine_init_bf16<<<dim3(1024), blk, 0, stream>>>(h0a, c0, h1a, c1, x, dh0, dc, din);

    // ---- decoder: 2 launches per step ----
    for (int t = 0; t < TOUT; ++t) {
        const ushort* dhin = (t & 1) ? dh1 : dh0;
        ushort*       dhout = (t & 1) ? dh0 : dh1;
        dec_fused<<<dim3(256), blk, 0, stream>>>(
            dhin, dhout, wdWhh, dWih, din, dbih, dbhh, dc,
            wf1W, f1b, winW, inb, ubuf, dbuf, qbuf, kbuf, vwb);
        attn_fused<<<dim3(512), blk, 0, stream>>>(
            qbuf, kbuf, vwb, ccb, out, din, t);
    }
    (void)in_sizes; (void)n_in; (void)out_size; (void)ws_size;
}